// Round 6
// baseline (373.927 us; speedup 1.0000x reference)
//
#include <hip/hip_runtime.h>

// PolyPoolerTextLenSensitive — MI355X (gfx950)
//
// R5 = R2 (best: staged, pow2-stride, 0 bank conflicts, ~95-105 µs) plus:
//  1. T14 async-STAGE split: next round's patch is global-loaded into
//     registers BEFORE computing the current round from LDS; ds_write after
//     the read barrier. Statically unrolled MAXIT guard loop (no scratch).
//  2. dwordx4 nt output stores: each thread owns 4 consecutive positions of
//     one channel slot (wave = 1 KB contiguous store).
//  3. XCD-locality block decode: flat grid, box = n & 255 -> all 16 blocks
//     of one box share box%8 => same XCD L2 (8x less duplicate patch fetch).
// R4 post-mortem: direct gather + max TLP (~120 µs) < staged (~95) — keep
// staging; attack the stage->barrier->compute serial chain instead.

#define NBOX 256
#define NCH  256
#define CCHUNK 32
#define NSTG 4
#define PMAX 2560              // floats per staged channel patch (pow2 stride)
#define MAXIT 5                // ceil(PMAX / 512) staging iters per thread
#define OUT0_ELEMS ((size_t)NBOX * NCH * 8 * 32)

typedef float f32x4 __attribute__((ext_vector_type(4)));

// Bilinear geometry for one grid position: tap offsets (patch- or global-
// space via pxo/pyo/PWe) + mask-folded weights.
__device__ __forceinline__ void make_geo(
    const float* __restrict__ pts, int pos, int lwp, int W, int H,
    int pxo, int pyo, int PWe,
    int* __restrict__ off, float* __restrict__ wt)
{
    const int wp = 1 << lwp;
    const int i  = pos >> lwp;
    const int j  = pos & (wp - 1);

    // boundary interp parameter (n-1 = 6 segments)
    float u  = ((j + 0.5f) / (float)wp) * 6.0f;
    int   i0 = (int)floorf(u);
    i0 = min(max(i0, 0), 5);
    float f = u - (float)i0;

    const float inx = 1.0f / 1344.0f, iny = 1.0f / 800.0f;
    float txa = pts[2 * i0]     * inx, tya = pts[2 * i0 + 1] * iny;
    float txb = pts[2 * i0 + 2] * inx, tyb = pts[2 * i0 + 3] * iny;
    int ka = 13 - i0, kb = 12 - i0;                 // reversed bottom points
    float bxa = pts[2 * ka] * inx, bya = pts[2 * ka + 1] * iny;
    float bxb = pts[2 * kb] * inx, byb = pts[2 * kb + 1] * iny;

    float topx = txa * (1.0f - f) + txb * f;
    float topy = tya * (1.0f - f) + tyb * f;
    float botx = bxa * (1.0f - f) + bxb * f;
    float boty = bya * (1.0f - f) + byb * f;

    float v  = (i + 0.5f) / 8.0f;
    float gx = topx * (1.0f - v) + botx * v;
    float gy = topy * (1.0f - v) + boty * v;

    float x = gx * (float)W - 0.5f;
    float y = gy * (float)H - 0.5f;
    float x0f = floorf(x), y0f = floorf(y);
    float fx = x - x0f,   fy = y - y0f;
    int x0 = (int)x0f, y0 = (int)y0f;
    int x1 = x0 + 1,   y1 = y0 + 1;

    int x0c = min(max(x0, 0), W - 1), x1c = min(max(x1, 0), W - 1);
    int y0c = min(max(y0, 0), H - 1), y1c = min(max(y1, 0), H - 1);
    float m00 = (x0 >= 0 && x0 < W && y0 >= 0 && y0 < H) ? 1.0f : 0.0f;
    float m10 = (x1 >= 0 && x1 < W && y0 >= 0 && y0 < H) ? 1.0f : 0.0f;
    float m01 = (x0 >= 0 && x0 < W && y1 >= 0 && y1 < H) ? 1.0f : 0.0f;
    float m11 = (x1 >= 0 && x1 < W && y1 >= 0 && y1 < H) ? 1.0f : 0.0f;

    off[0] = (y0c - pyo) * PWe + (x0c - pxo);
    off[1] = (y0c - pyo) * PWe + (x1c - pxo);
    off[2] = (y1c - pyo) * PWe + (x0c - pxo);
    off[3] = (y1c - pyo) * PWe + (x1c - pxo);
    wt[0] = (1.0f - fx) * (1.0f - fy) * m00;
    wt[1] = fx * (1.0f - fy) * m10;
    wt[2] = (1.0f - fx) * fy * m01;
    wt[3] = fx * fy * m11;
}

__global__ __launch_bounds__(256) void poly_pool_kernel(
    const float* __restrict__ f0, const float* __restrict__ f1,
    const float* __restrict__ f2, const float* __restrict__ f3,
    const float* __restrict__ polys, const int* __restrict__ img_ids,
    const int* __restrict__ lens, float* __restrict__ out)
{
    // flat decode: all 16 blocks of a box share (box % 8) -> same XCD L2
    const int n    = blockIdx.x;
    const int b    = n & (NBOX - 1);
    const int slab = n >> 8;               // 0..15
    const int cxb  = slab & 7;
    const int pidk = slab >> 3;            // 0 -> (8,32), 1 -> (8,64)
    const int lwp  = 5 + pidk;
    const int npos = 8 << lwp;             // 256 or 512
    const int c0   = cxb * CCHUNK;
    const int tid  = threadIdx.x;

    float* outb = out + (pidk ? OUT0_ELEMS : (size_t)0) + (size_t)b * NCH * npos;

    // pooler routing: pooler_id = (lens > 8)
    const int pooler = (lens[b] > 8) ? 1 : 0;
    if (pooler != pidk) {
        // this box contributes zeros to this output tensor — 16B nt stores
        f32x4 z = (f32x4)(0.0f);
        f32x4* p = reinterpret_cast<f32x4*>(outb + (size_t)c0 * npos);
        const int total4 = (CCHUNK * npos) >> 2;   // 2048 or 4096
        for (int k = tid; k < total4; k += 256)
            __builtin_nontemporal_store(z, p + k);
        return;
    }

    __shared__ float pts[28];               // polys[b] : 14 points x 2
    __shared__ float patch[NSTG][PMAX];     // 40 KB staging
    if (tid < 28) pts[tid] = polys[b * 28 + tid];
    __syncthreads();

    // ---- level selection: s = sqrt(dx*dy) over raw points ----
    float minx = pts[0], maxx = pts[0], miny = pts[1], maxy = pts[1];
#pragma unroll
    for (int k = 1; k < 14; ++k) {
        float x = pts[2 * k], y = pts[2 * k + 1];
        minx = fminf(minx, x); maxx = fmaxf(maxx, x);
        miny = fminf(miny, y); maxy = fmaxf(maxy, y);
    }
    float s = sqrtf((maxx - minx) * (maxy - miny));
    int lvl = (int)floorf(4.0f + log2f(s / 224.0f + 1e-6f));
    lvl = min(max(lvl, 2), 5) - 2;

    const float* feat; int H, W;
    switch (lvl) {
        case 0:  feat = f0; H = 200; W = 336; break;
        case 1:  feat = f1; H = 100; W = 168; break;
        case 2:  feat = f2; H = 50;  W = 84;  break;
        default: feat = f3; H = 25;  W = 42;  break;
    }
    const int HW = H * W;
    const float* featimg = feat + (size_t)img_ids[b] * NCH * HW;

    // ---- patch bounding box in feature coords (grid is convex in poly pts)
    float sxn = (float)W / 1344.0f, syn = (float)H / 800.0f;
    int px0 = min(max((int)floorf(minx * sxn - 0.5f), 0), W - 1);
    int px1 = min(max((int)floorf(maxx * sxn - 0.5f) + 1, 0), W - 1);
    int py0 = min(max((int)floorf(miny * syn - 0.5f), 0), H - 1);
    int py1 = min(max((int)floorf(maxy * syn - 0.5f) + 1, 0), H - 1);
    const int PW = px1 - px0 + 1;
    const int PH = py1 - py0 + 1;
    const int lg = (PW <= 64) ? 6 : ((PW <= 128) ? 7 : 8);
    const int PWP = 1 << lg;
    const int npatch = PH << lg;
    const bool staged = (PW <= 256) && (npatch <= PMAX);  // uniform per block

    const int pxo = staged ? px0 : 0;
    const int pyo = staged ? py0 : 0;
    const int PWe = staged ? PWP : W;      // !staged -> offsets are global

    // ---- geometry: thread -> (channel slot, 4 consecutive positions) ----
    const int groups = npos >> 2;          // 64 or 128
    const int pg     = tid & (groups - 1);
    const int csub   = tid / groups;       // pid0: 0..3, pid1: 0..1
    const int npass  = pidk ? 2 : 1;

    int   off[4][4];
    float wt [4][4];
#pragma unroll
    for (int k = 0; k < 4; ++k)
        make_geo(pts, 4 * pg + k, lwp, W, H, pxo, pyo, PWe, off[k], wt[k]);

    float* opb = outb + 4 * pg;

    if (staged) {
        // T14 prefetch pipeline: regs <- round r+1 while computing round r.
        float pfa[MAXIT][NSTG], pfb[MAXIT][NSTG];

#define PREFETCH(RR)                                                          \
        { const float* sb = featimg + (size_t)(c0 + (RR) * NSTG) * HW         \
                            + (size_t)py0 * W + px0;                          \
          _Pragma("unroll")                                                   \
          for (int it = 0; it < MAXIT; ++it) {                                \
              int e = tid + it * 512;                                         \
              if (e < npatch) {                                               \
                  int eb = min(e + 256, npatch - 1);                          \
                  int ra = e  >> lg, ca = min(e  & (PWP - 1), PW - 1);        \
                  int rb = eb >> lg, cb = min(eb & (PWP - 1), PW - 1);        \
                  const float* sA = sb + ra * W + ca;                         \
                  const float* sB = sb + rb * W + cb;                         \
                  pfa[it][0] = sA[0];      pfa[it][1] = sA[HW];               \
                  pfa[it][2] = sA[2 * HW]; pfa[it][3] = sA[3 * HW];           \
                  pfb[it][0] = sB[0];      pfb[it][1] = sB[HW];               \
                  pfb[it][2] = sB[2 * HW]; pfb[it][3] = sB[3 * HW];           \
              } } }

#define WRITELDS                                                              \
        { _Pragma("unroll")                                                   \
          for (int it = 0; it < MAXIT; ++it) {                                \
              int e = tid + it * 512;                                         \
              if (e < npatch) {                                               \
                  int eb = min(e + 256, npatch - 1);                          \
                  patch[0][e]  = pfa[it][0]; patch[1][e]  = pfa[it][1];       \
                  patch[2][e]  = pfa[it][2]; patch[3][e]  = pfa[it][3];       \
                  patch[0][eb] = pfb[it][0]; patch[1][eb] = pfb[it][1];       \
                  patch[2][eb] = pfb[it][2]; patch[3][eb] = pfb[it][3];       \
              } } }

        PREFETCH(0);
        WRITELDS;
        __syncthreads();

        for (int rnd = 0; rnd < CCHUNK / NSTG; ++rnd) {
            if (rnd + 1 < CCHUNK / NSTG) PREFETCH(rnd + 1);   // issue early

            for (int cc = 0; cc < npass; ++cc) {
                const int slot = pidk ? ((cc << 1) + csub) : csub;
                const float* pk = patch[slot];
                f32x4 res;
#pragma unroll
                for (int k = 0; k < 4; ++k)
                    res[k] = wt[k][0] * pk[off[k][0]] + wt[k][1] * pk[off[k][1]]
                           + wt[k][2] * pk[off[k][2]] + wt[k][3] * pk[off[k][3]];
                const int ch = c0 + rnd * NSTG + slot;
                __builtin_nontemporal_store(res,
                    reinterpret_cast<f32x4*>(opb + (size_t)ch * npos));
            }
            __syncthreads();                      // done reading patch[rnd]
            if (rnd + 1 < CCHUNK / NSTG) {
                WRITELDS;                         // vmcnt drained under compute
                __syncthreads();                  // patch[rnd+1] ready
            }
        }
    } else {
        // fallback: direct global gather (offsets are global here)
        for (int rnd = 0; rnd < CCHUNK / NSTG; ++rnd) {
            for (int cc = 0; cc < npass; ++cc) {
                const int slot = pidk ? ((cc << 1) + csub) : csub;
                const int ch = c0 + rnd * NSTG + slot;
                const float* fc = featimg + (size_t)ch * HW;
                f32x4 res;
#pragma unroll
                for (int k = 0; k < 4; ++k)
                    res[k] = wt[k][0] * fc[off[k][0]] + wt[k][1] * fc[off[k][1]]
                           + wt[k][2] * fc[off[k][2]] + wt[k][3] * fc[off[k][3]];
                __builtin_nontemporal_store(res,
                    reinterpret_cast<f32x4*>(opb + (size_t)ch * npos));
            }
        }
    }
}

extern "C" void kernel_launch(void* const* d_in, const int* in_sizes, int n_in,
                              void* d_out, int out_size, void* d_ws, size_t ws_size,
                              hipStream_t stream) {
    const float* f0    = (const float*)d_in[0];
    const float* f1    = (const float*)d_in[1];
    const float* f2    = (const float*)d_in[2];
    const float* f3    = (const float*)d_in[3];
    const float* polys = (const float*)d_in[4];
    const int*   ids   = (const int*)d_in[5];
    const int*   lens  = (const int*)d_in[6];
    float* out = (float*)d_out;

    poly_pool_kernel<<<dim3(4096), 256, 0, stream>>>(f0, f1, f2, f3,
                                                     polys, ids, lens, out);
}